// Round 13
// baseline (34.601 us; speedup 1.0000x reference)
//
#include <hip/hip_runtime.h>
#include <hip/hip_fp16.h>
#include <math.h>

#define RESN 2048
#define TEXW 1024
#define PW 514            // packed table width  (x0 in [511,1023] -> rx in [0,512], +1 -> 513)
#define PH 1025           // packed table height (y0 in [0,1023], y1 -> 1024 = wrap row)
#define PREC (PH * PW)    // 526,850 records * 16B = 8,429,600 bytes

// atan2 for y >= 0, returns [0, pi]. Cephes-style. Peak err ~2e-7 rad.
__device__ __forceinline__ float fatan2_pos(float y, float x) {
    float ax = fabsf(x);
    float mn = fminf(ax, y);
    float mx = fmaxf(ax, y);
    float r0 = __builtin_amdgcn_rcpf(mx);
    r0 = r0 * __builtin_fmaf(-mx, r0, 2.0f);
    float a = mn * r0;
    bool red = a > 0.41421356f;
    float t = (a - 1.0f) * __builtin_amdgcn_rcpf(a + 1.0f);
    float w = red ? t : a;
    float s = w * w;
    float p = __builtin_fmaf(s, 8.05374449538e-2f, -1.38776856032e-1f);
    p = __builtin_fmaf(s, p, 1.99777106478e-1f);
    p = __builtin_fmaf(s, p, -3.33329491539e-1f);
    float r = __builtin_fmaf(w * s, p, w);
    r = red ? r + 0.78539816339f : r;
    r = (y > ax) ? 1.57079632679f - r : r;
    r = (x < 0.0f) ? 3.14159265359f - r : r;
    return r;
}

struct __align__(4) F3 { float x, y, z; };
union HU { uint4 v; __half h[8]; };

// ---- repack: fuse tex+nmap used-half into fp16 16B records (one launch-local table) ----
__global__ __launch_bounds__(256) void repack(const float* __restrict__ tex,
                                              const float* __restrict__ nmap,
                                              uint4* __restrict__ rec) {
    int idx = blockIdx.x * 256 + threadIdx.x;
    if (idx >= PREC) return;
    int y  = idx / PW;
    int rx = idx - y * PW;
    int sx = (rx + 511) & (TEXW - 1);     // rx=513 -> 1024 -> 0 (x-wrap dup)
    int sy = y & (TEXW - 1);              // y=1024 -> 0 (y-wrap dup)
    int s = (sy * TEXW + sx) * 3;
    HU u;
    u.h[0] = __float2half(tex[s + 0]);
    u.h[1] = __float2half(tex[s + 1]);
    u.h[2] = __float2half(tex[s + 2]);
    u.h[3] = __float2half(nmap[s + 0]);
    u.h[4] = __float2half(nmap[s + 1]);
    u.h[5] = __float2half(nmap[s + 2]);
    u.h[6] = __float2half(0.0f);
    u.h[7] = __float2half(0.0f);
    rec[idx] = u.v;
}

// blend 6 channels from 4 fp16 records
#define BLEND6(c00, c01, c10, c11, w00, w01, w10, w11, ar, ag, ab, tnx, tny, tnz)          \
    ar  = __half2float(c00.h[0])*w00 + __half2float(c01.h[0])*w01                          \
        + __half2float(c10.h[0])*w10 + __half2float(c11.h[0])*w11;                         \
    ag  = __half2float(c00.h[1])*w00 + __half2float(c01.h[1])*w01                          \
        + __half2float(c10.h[1])*w10 + __half2float(c11.h[1])*w11;                         \
    ab  = __half2float(c00.h[2])*w00 + __half2float(c01.h[2])*w01                          \
        + __half2float(c10.h[2])*w10 + __half2float(c11.h[2])*w11;                         \
    tnx = (__half2float(c00.h[3])*w00 + __half2float(c01.h[3])*w01                         \
        +  __half2float(c10.h[3])*w10 + __half2float(c11.h[3])*w11) * 2.0f - 1.0f;         \
    tny = (__half2float(c00.h[4])*w00 + __half2float(c01.h[4])*w01                         \
        +  __half2float(c10.h[4])*w10 + __half2float(c11.h[4])*w11) * 2.0f - 1.0f;         \
    tnz = (__half2float(c00.h[5])*w00 + __half2float(c01.h[5])*w01                         \
        +  __half2float(c10.h[5])*w10 + __half2float(c11.h[5])*w11) * 2.0f - 1.0f;

#define SHADE(nx, z, tnx, tny, tnz, ar, ag, ab, inx, o)                                    \
    {                                                                                      \
        float snx = nx * egg, sny = ny, snz = z * egg;                                     \
        float sl2 = snx*snx + sny*sny + snz*snz;                                           \
        float isl = __builtin_amdgcn_rsqf(sl2);                                            \
        float bnx = snx * isl, bny = sny * isl, bnz = snz * isl;                           \
        bool use_right = fabsf(bny) > 0.99f;                                               \
        float d = use_right ? bnx : bny;                                                   \
        float m = use_right ? bny : bnx;                                                   \
        float q2 = m * m + bnz * bnz;                                                      \
        float iq = __builtin_amdgcn_rsqf(q2);                                              \
        float q  = q2 * iq;                                                                \
        float e  = -(d * iq);                                                              \
        float tzv = bnz * e;                                                               \
        float tx = use_right ? q : (bnx * e);                                              \
        float ty = use_right ? (bny * e) : q;                                              \
        float bx = use_right ? 0.0f        : -(bnz * iq);                                  \
        float by = use_right ? (bnz * iq)  : 0.0f;                                         \
        float bz = use_right ? -(bny * iq) : (bnx * iq);                                   \
        float wx = tnx * tx + tny * bx + tnz * bnx;                                        \
        float wy = tnx * ty + tny * by + tnz * bny;                                        \
        float wz = tnx * tzv + tny * bz + tnz * bnz;                                       \
        float wl2 = wx*wx + wy*wy + wz*wz;                                                 \
        float iwl = __builtin_amdgcn_rsqf(fmaxf(wl2, 1e-12f));                             \
        wx *= iwl; wy *= iwl; wz *= iwl;                                                   \
        float ndotl = fmaxf(wx * Lx + wy * Ly + wz * Lz, 0.0f);                            \
        float ndoth = fmaxf(wx * Hx + wy * Hy + wz * Hz, 0.0f);                            \
        float s2 = ndoth * ndoth, s4 = s2 * s2, s8 = s4 * s4, s16 = s8 * s8;               \
        float spec = s16 * s16;                                                            \
        float ndotv = fmaxf(wz, 0.0f);                                                     \
        float t1 = 1.0f - ndotv;                                                           \
        float t2v = t1 * t1, t4v = t2v * t2v;                                              \
        float fres = 0.04f + 0.96f * (t4v * t1);                                           \
        float ka = 0.1f + ndotl;                                                           \
        float add = spec * fres;                                                           \
        o[0] = inx ? fminf(fmaxf(__builtin_fmaf(ar, ka, add), 0.0f), 1.0f) : 0.0f;         \
        o[1] = inx ? fminf(fmaxf(__builtin_fmaf(ag, ka, add), 0.0f), 1.0f) : 0.0f;         \
        o[2] = inx ? fminf(fmaxf(__builtin_fmaf(ab, ka, add), 0.0f), 1.0f) : 0.0f;         \
    }

__global__ __launch_bounds__(256) void egg_render_packed(
    const uint4* __restrict__ rec,
    float* __restrict__ out)
{
    // 2 px/thread pipeline; 4 dwordx4 gathers per pixel from the fused
    // fp16 table (vs 8 dwordx3 from two f32 textures) -> ~4x fewer
    // L1 line-lookups, which R0-R11 evidence says is the bottleneck.
    int t = blockIdx.x * 256 + threadIdx.x;
    int j = t >> 10;
    int tr = t & 1023;
    int iA = ((tr >> 6) << 7) + (tr & 63);
    int iB = iA + 64;
    float* oA = out + ((size_t)j * RESN + iA) * 3u;
    float* oB = oA + 192u;

    const float invres = 1.0f / (float)RESN;
    float ny = __fmul_rn(__fsub_rn(0.5f, __fmul_rn((float)j, invres)), 2.0f) / 0.85f;
    float nysq = __fmul_rn(ny, ny);

    if (!(nysq <= 1.0f)) {
        oA[0] = 0.f; oA[1] = 0.f; oA[2] = 0.f;
        oB[0] = 0.f; oB[1] = 0.f; oB[2] = 0.f;
        return;
    }

    float egg = 1.0f - 0.25f * ny;
    float sphi = sqrtf(fmaxf(__builtin_fmaf(-ny, ny, 1.0f), 0.0f));
    float phi = fatan2_pos(sphi, ny);
    float v = phi * 0.3183098861837907f;          // in [0,1], floor unneeded
    float yy = v * (float)TEXW - 0.5f;
    float yf = floorf(yy);
    float fy = yy - yf;
    float gy = 1.0f - fy;
    int y0 = (int)yf & (TEXW - 1);                // [-1,1023] -> [0,1023]
    int rb0 = y0 * PW;
    int rb1 = rb0 + PW;                           // y1 = y0+1 <= 1024 (wrap row)

    // ---- pixel A address math ----
    float nxA = __fmul_rn(__fsub_rn(__fmul_rn((float)iA, invres), 0.5f), 2.0f) / 0.85f;
    float rsqA = __fadd_rn(__fmul_rn(nxA, nxA), nysq);
    bool inA = (rsqA <= 1.0f);
    float zA = sqrtf(fmaxf(__fsub_rn(1.0f, rsqA), 0.0f));
    float thetaA = fatan2_pos(zA, nxA);
    float uA = thetaA * 0.15915494309189535f + 0.5f;   // [0.5,1.0]
    float xxA = uA * (float)TEXW - 0.5f;               // [511.5,1023.5]
    float xfA = floorf(xxA);
    float fxA = xxA - xfA;
    float gxA = 1.0f - fxA;
    int rxA = min(max((int)xfA - 511, 0), 512);        // clamp = cheap insurance
    float w00A = gxA * gy, w01A = fxA * gy, w10A = gxA * fy, w11A = fxA * fy;

    // ---- issue A's 4 gathers ----
    HU cA00, cA01, cA10, cA11;
    cA00.v = rec[rb0 + rxA];
    cA01.v = rec[rb0 + rxA + 1];
    cA10.v = rec[rb1 + rxA];
    cA11.v = rec[rb1 + rxA + 1];

    // ---- pixel B address math (covers A's flight) ----
    float nxB = __fmul_rn(__fsub_rn(__fmul_rn((float)iB, invres), 0.5f), 2.0f) / 0.85f;
    float rsqB = __fadd_rn(__fmul_rn(nxB, nxB), nysq);
    bool inB = (rsqB <= 1.0f);
    float zB = sqrtf(fmaxf(__fsub_rn(1.0f, rsqB), 0.0f));
    float thetaB = fatan2_pos(zB, nxB);
    float uB = thetaB * 0.15915494309189535f + 0.5f;
    float xxB = uB * (float)TEXW - 0.5f;
    float xfB = floorf(xxB);
    float fxB = xxB - xfB;
    float gxB = 1.0f - fxB;
    int rxB = min(max((int)xfB - 511, 0), 512);
    float w00B = gxB * gy, w01B = fxB * gy, w10B = gxB * fy, w11B = fxB * fy;

    // ---- issue B's 4 gathers (shade A covers their flight) ----
    HU cB00, cB01, cB10, cB11;
    cB00.v = rec[rb0 + rxB];
    cB01.v = rec[rb0 + rxB + 1];
    cB10.v = rec[rb1 + rxB];
    cB11.v = rec[rb1 + rxB + 1];

    // lighting constants (compile-time folded, f32 semantics)
    float Lx = 0.5f, Ly = 0.7f, Lz = 1.0f;
    float ll = sqrtf(Lx * Lx + Ly * Ly + Lz * Lz);
    Lx /= ll; Ly /= ll; Lz /= ll;
    float Hx = Lx, Hy = Ly, Hz = Lz + 1.0f;
    float hl = sqrtf(Hx * Hx + Hy * Hy + Hz * Hz);
    Hx /= hl; Hy /= hl; Hz /= hl;

    {
        float ar, ag, ab, tnx, tny, tnz;
        BLEND6(cA00, cA01, cA10, cA11, w00A, w01A, w10A, w11A, ar, ag, ab, tnx, tny, tnz)
        SHADE(nxA, zA, tnx, tny, tnz, ar, ag, ab, inA, oA)
    }
    {
        float ar, ag, ab, tnx, tny, tnz;
        BLEND6(cB00, cB01, cB10, cB11, w00B, w01B, w10B, w11B, ar, ag, ab, tnx, tny, tnz)
        SHADE(nxB, zB, tnx, tny, tnz, ar, ag, ab, inB, oB)
    }
}

// ---- fallback: exact R11 kernel (used only if ws_size is too small) ----
__global__ __launch_bounds__(256) void egg_render_fb(
    const float* __restrict__ tex,
    const float* __restrict__ nmap,
    float* __restrict__ out)
{
    int t = blockIdx.x * 256 + threadIdx.x;
    int j = t >> 10;
    int tr = t & 1023;
    int iA = ((tr >> 6) << 7) + (tr & 63);
    int iB = iA + 64;
    float* oA = out + ((size_t)j * RESN + iA) * 3u;
    float* oB = oA + 192u;

    const float invres = 1.0f / (float)RESN;
    float ny = __fmul_rn(__fsub_rn(0.5f, __fmul_rn((float)j, invres)), 2.0f) / 0.85f;
    float nysq = __fmul_rn(ny, ny);

    if (!(nysq <= 1.0f)) {
        oA[0] = 0.f; oA[1] = 0.f; oA[2] = 0.f;
        oB[0] = 0.f; oB[1] = 0.f; oB[2] = 0.f;
        return;
    }

    float egg = 1.0f - 0.25f * ny;
    float sphi = sqrtf(fmaxf(__builtin_fmaf(-ny, ny, 1.0f), 0.0f));
    float phi = fatan2_pos(sphi, ny);
    float v = phi * 0.3183098861837907f;
    float yy = v * (float)TEXW - 0.5f;
    float yf = floorf(yy);
    float fy = yy - yf;
    float gy = 1.0f - fy;
    int y0 = (int)yf & (TEXW - 1);
    int y1 = (y0 + 1) & (TEXW - 1);
    int rb0 = y0 * TEXW;
    int rb1 = y1 * TEXW;

    float nxA = __fmul_rn(__fsub_rn(__fmul_rn((float)iA, invres), 0.5f), 2.0f) / 0.85f;
    float rsqA = __fadd_rn(__fmul_rn(nxA, nxA), nysq);
    bool inA = (rsqA <= 1.0f);
    float zA = sqrtf(fmaxf(__fsub_rn(1.0f, rsqA), 0.0f));
    float thetaA = fatan2_pos(zA, nxA);
    float uA = thetaA * 0.15915494309189535f + 0.5f;
    float xxA = uA * (float)TEXW - 0.5f;
    float xfA = floorf(xxA);
    float fxA = xxA - xfA;
    float gxA = 1.0f - fxA;
    int x0A = (int)xfA & (TEXW - 1);
    int x1A = (x0A + 1) & (TEXW - 1);
    float w00A = gxA * gy, w01A = fxA * gy, w10A = gxA * fy, w11A = fxA * fy;
    int o00A = (rb0 + x0A) * 3, o01A = (rb0 + x1A) * 3;
    int o10A = (rb1 + x0A) * 3, o11A = (rb1 + x1A) * 3;

    F3 aA00 = *(const F3*)(tex + o00A);
    F3 aA01 = *(const F3*)(tex + o01A);
    F3 aA10 = *(const F3*)(tex + o10A);
    F3 aA11 = *(const F3*)(tex + o11A);
    F3 nA00 = *(const F3*)(nmap + o00A);
    F3 nA01 = *(const F3*)(nmap + o01A);
    F3 nA10 = *(const F3*)(nmap + o10A);
    F3 nA11 = *(const F3*)(nmap + o11A);

    float nxB = __fmul_rn(__fsub_rn(__fmul_rn((float)iB, invres), 0.5f), 2.0f) / 0.85f;
    float rsqB = __fadd_rn(__fmul_rn(nxB, nxB), nysq);
    bool inB = (rsqB <= 1.0f);
    float zB = sqrtf(fmaxf(__fsub_rn(1.0f, rsqB), 0.0f));
    float thetaB = fatan2_pos(zB, nxB);
    float uB = thetaB * 0.15915494309189535f + 0.5f;
    float xxB = uB * (float)TEXW - 0.5f;
    float xfB = floorf(xxB);
    float fxB = xxB - xfB;
    float gxB = 1.0f - fxB;
    int x0B = (int)xfB & (TEXW - 1);
    int x1B = (x0B + 1) & (TEXW - 1);
    float w00B = gxB * gy, w01B = fxB * gy, w10B = gxB * fy, w11B = fxB * fy;
    int o00B = (rb0 + x0B) * 3, o01B = (rb0 + x1B) * 3;
    int o10B = (rb1 + x0B) * 3, o11B = (rb1 + x1B) * 3;

    F3 aB00 = *(const F3*)(tex + o00B);
    F3 aB01 = *(const F3*)(tex + o01B);
    F3 aB10 = *(const F3*)(tex + o10B);
    F3 aB11 = *(const F3*)(tex + o11B);
    F3 nB00 = *(const F3*)(nmap + o00B);
    F3 nB01 = *(const F3*)(nmap + o01B);
    F3 nB10 = *(const F3*)(nmap + o10B);
    F3 nB11 = *(const F3*)(nmap + o11B);

    float Lx = 0.5f, Ly = 0.7f, Lz = 1.0f;
    float ll = sqrtf(Lx * Lx + Ly * Ly + Lz * Lz);
    Lx /= ll; Ly /= ll; Lz /= ll;
    float Hx = Lx, Hy = Ly, Hz = Lz + 1.0f;
    float hl = sqrtf(Hx * Hx + Hy * Hy + Hz * Hz);
    Hx /= hl; Hy /= hl; Hz /= hl;

    {
        float ar = aA00.x*w00A + aA01.x*w01A + aA10.x*w10A + aA11.x*w11A;
        float ag = aA00.y*w00A + aA01.y*w01A + aA10.y*w10A + aA11.y*w11A;
        float ab = aA00.z*w00A + aA01.z*w01A + aA10.z*w10A + aA11.z*w11A;
        float tnx = (nA00.x*w00A + nA01.x*w01A + nA10.x*w10A + nA11.x*w11A) * 2.0f - 1.0f;
        float tny = (nA00.y*w00A + nA01.y*w01A + nA10.y*w10A + nA11.y*w11A) * 2.0f - 1.0f;
        float tnz = (nA00.z*w00A + nA01.z*w01A + nA10.z*w10A + nA11.z*w11A) * 2.0f - 1.0f;
        SHADE(nxA, zA, tnx, tny, tnz, ar, ag, ab, inA, oA)
    }
    {
        float ar = aB00.x*w00B + aB01.x*w01B + aB10.x*w10B + aB11.x*w11B;
        float ag = aB00.y*w00B + aB01.y*w01B + aB10.y*w10B + aB11.y*w11B;
        float ab = aB00.z*w00B + aB01.z*w01B + aB10.z*w10B + aB11.z*w11B;
        float tnx = (nB00.x*w00B + nB01.x*w01B + nB10.x*w10B + nB11.x*w11B) * 2.0f - 1.0f;
        float tny = (nB00.y*w00B + nB01.y*w01B + nB10.y*w10B + nB11.y*w11B) * 2.0f - 1.0f;
        float tnz = (nB00.z*w00B + nB01.z*w01B + nB10.z*w10B + nB11.z*w11B) * 2.0f - 1.0f;
        SHADE(nxB, zB, tnx, tny, tnz, ar, ag, ab, inB, oB)
    }
}

extern "C" void kernel_launch(void* const* d_in, const int* in_sizes, int n_in,
                              void* d_out, int out_size, void* d_ws, size_t ws_size,
                              hipStream_t stream) {
    const float* tex  = (const float*)d_in[0];
    const float* nmap = (const float*)d_in[1];
    float* out = (float*)d_out;
    int total_threads = RESN * RESN / 2;

    if (ws_size >= (size_t)PREC * 16u) {
        uint4* rec = (uint4*)d_ws;
        hipLaunchKernelGGL(repack, dim3((PREC + 255) / 256), dim3(256), 0, stream,
                           tex, nmap, rec);
        hipLaunchKernelGGL(egg_render_packed, dim3(total_threads / 256), dim3(256),
                           0, stream, rec, out);
    } else {
        hipLaunchKernelGGL(egg_render_fb, dim3(total_threads / 256), dim3(256),
                           0, stream, tex, nmap, out);
    }
}

// Round 14
// 28.534 us; speedup vs baseline: 1.2126x; 1.2126x over previous
//
#include <hip/hip_runtime.h>
#include <math.h>

#define RESN 2048
#define TEXW 1024

// atan2 for y >= 0, returns [0, pi]. Cephes-style. Peak err ~2e-7 rad.
__device__ __forceinline__ float fatan2_pos(float y, float x) {
    float ax = fabsf(x);
    float mn = fminf(ax, y);
    float mx = fmaxf(ax, y);
    float r0 = __builtin_amdgcn_rcpf(mx);
    r0 = r0 * __builtin_fmaf(-mx, r0, 2.0f);
    float a = mn * r0;
    bool red = a > 0.41421356f;
    float t = (a - 1.0f) * __builtin_amdgcn_rcpf(a + 1.0f);
    float w = red ? t : a;
    float s = w * w;
    float p = __builtin_fmaf(s, 8.05374449538e-2f, -1.38776856032e-1f);
    p = __builtin_fmaf(s, p, 1.99777106478e-1f);
    p = __builtin_fmaf(s, p, -3.33329491539e-1f);
    float r = __builtin_fmaf(w * s, p, w);
    r = red ? r + 0.78539816339f : r;
    r = (y > ax) ? 1.57079632679f - r : r;
    r = (x < 0.0f) ? 3.14159265359f - r : r;
    return r;
}

__global__ __launch_bounds__(512) void egg_render(
    const float* __restrict__ tex,
    const float* __restrict__ nmap,
    float* __restrict__ out)
{
    // One block per image row. Key fact: per row, v is constant -> ALL
    // samples hit exactly 2 texture rows, x in [511,1024] (u in [0.5,1]).
    // Stage 4x514 texels (tex+nmap x y0,y1) into LDS via coalesced reads;
    // bilinear gathers become ds_read_b128 (DS pipe, overlaps VALU+VMEM).
    int j = blockIdx.x;
    int tid = threadIdx.x;
    float* orow = out + (size_t)j * RESN * 3u;

    const float invres = 1.0f / (float)RESN;
    // bit-exact vs numpy on the inside-test path: no fma contraction,
    // true IEEE division by 0.85
    float ny = __fmul_rn(__fsub_rn(0.5f, __fmul_rn((float)j, invres)), 2.0f) / 0.85f;
    float nysq = __fmul_rn(ny, ny);

    if (!(nysq <= 1.0f)) {                        // whole row outside the disc
        #pragma unroll
        for (int k = 0; k < 4; ++k) {
            float* o = orow + ((k << 9) + tid) * 3;
            o[0] = 0.f; o[1] = 0.f; o[2] = 0.f;
        }
        return;
    }

    // ---- row-shared math (wave-uniform) ----
    float egg = 1.0f - 0.25f * ny;                // in [0.75, 1.25]
    float sphi = sqrtf(fmaxf(__builtin_fmaf(-ny, ny, 1.0f), 0.0f));
    float phi = fatan2_pos(sphi, ny);             // == acos(ny)
    float v = phi * 0.3183098861837907f;          // /pi, in [0,1]; floor unneeded
    float yy = v * (float)TEXW - 0.5f;
    float yf = floorf(yy);
    float fy = yy - yf;
    float gy = 1.0f - fy;
    int y0 = (int)yf & (TEXW - 1);
    int y1 = (y0 + 1) & (TEXW - 1);

    // ---- stage the 4 row-segments into LDS (coalesced global reads) ----
    // lds[0]=tex@y0, lds[1]=tex@y1, lds[2]=nmap@y0, lds[3]=nmap@y1
    __shared__ float4 lds[4][516];                // 33KB -> 4 blocks/CU
    for (int f = tid; f < 4 * 514; f += 512) {
        int mr = f >> 9;                          // careful: 514 not pow2 -> do exact
        mr = f / 514;
        int c = f - mr * 514;
        int sy = (mr & 1) ? y1 : y0;
        const float* src = ((mr & 2) ? nmap : tex) + ((sy << 10) + ((c + 511) & (TEXW - 1))) * 3;
        lds[mr][c] = make_float4(src[0], src[1], src[2], 0.0f);
    }
    __syncthreads();

    // lighting constants (compile-time folded, f32 semantics)
    float Lx = 0.5f, Ly = 0.7f, Lz = 1.0f;
    float ll = sqrtf(Lx * Lx + Ly * Ly + Lz * Lz);
    Lx /= ll; Ly /= ll; Lz /= ll;
    float Hx = Lx, Hy = Ly, Hz = Lz + 1.0f;
    float hl = sqrtf(Hx * Hx + Hy * Hy + Hz * Hz);
    Hx /= hl; Hy /= hl; Hz /= hl;

    // ---- 4 px/thread: px = k*512 + tid (adjacent lanes -> adjacent px) ----
    #pragma unroll
    for (int k = 0; k < 4; ++k) {
        int i = (k << 9) + tid;
        float* o = orow + (size_t)i * 3u;

        float nx = __fmul_rn(__fsub_rn(__fmul_rn((float)i, invres), 0.5f), 2.0f) / 0.85f;
        float rsq = __fadd_rn(__fmul_rn(nx, nx), nysq);
        bool ins = (rsq <= 1.0f);
        float z = sqrtf(fmaxf(__fsub_rn(1.0f, rsq), 0.0f));  // 0 for outside lanes

        float theta = fatan2_pos(z, nx);
        float u = theta * 0.15915494309189535f + 0.5f;       // [0.5,1.0]
        float xx = u * (float)TEXW - 0.5f;                   // [511.5,1023.5]
        float xf = floorf(xx);
        float fx = xx - xf;
        float gx = 1.0f - fx;
        int rx = min(max((int)xf - 511, 0), 512);            // LDS col; clamp = insurance
        float w00 = gx * gy, w01 = fx * gy, w10 = gx * fy, w11 = fx * fy;

        float4 t00 = lds[0][rx], t01 = lds[0][rx + 1];
        float4 t10 = lds[1][rx], t11 = lds[1][rx + 1];
        float4 n00 = lds[2][rx], n01 = lds[2][rx + 1];
        float4 n10 = lds[3][rx], n11 = lds[3][rx + 1];

        float ar = t00.x*w00 + t01.x*w01 + t10.x*w10 + t11.x*w11;
        float ag = t00.y*w00 + t01.y*w01 + t10.y*w10 + t11.y*w11;
        float ab = t00.z*w00 + t01.z*w01 + t10.z*w10 + t11.z*w11;
        float tnx = (n00.x*w00 + n01.x*w01 + n10.x*w10 + n11.x*w11) * 2.0f - 1.0f;
        float tny = (n00.y*w00 + n01.y*w01 + n10.y*w10 + n11.y*w11) * 2.0f - 1.0f;
        float tnz = (n00.z*w00 + n01.z*w01 + n10.z*w10 + n11.z*w11) * 2.0f - 1.0f;

        // analytical egg normal (|sn|^2 >= 0.5 for all lanes)
        float snx = nx * egg, sny = ny, snz = z * egg;
        float sl2 = snx*snx + sny*sny + snz*snz;
        float isl = __builtin_amdgcn_rsqf(sl2);
        float bnx = snx * isl, bny = sny * isl, bnz = snz * isl;

        // TBN closed form (== reference Gram-Schmidt + cross, both branches)
        bool use_right = fabsf(bny) > 0.99f;
        float d = use_right ? bnx : bny;
        float m = use_right ? bny : bnx;
        float q2 = m * m + bnz * bnz;
        float iq = __builtin_amdgcn_rsqf(q2);
        float q  = q2 * iq;
        float e  = -(d * iq);
        float tzv = bnz * e;
        float tx = use_right ? q : (bnx * e);
        float ty = use_right ? (bny * e) : q;
        float bx = use_right ? 0.0f        : -(bnz * iq);
        float by = use_right ? (bnz * iq)  : 0.0f;
        float bz = use_right ? -(bny * iq) : (bnx * iq);

        // perturbed normal; BUMP_STRENGTH = 1 -> nrm = normalize(world_n)
        float wx = tnx * tx + tny * bx + tnz * bnx;
        float wy = tnx * ty + tny * by + tnz * bny;
        float wz = tnx * tzv + tny * bz + tnz * bnz;
        float wl2 = wx*wx + wy*wy + wz*wz;
        float iwl = __builtin_amdgcn_rsqf(fmaxf(wl2, 1e-12f));
        wx *= iwl; wy *= iwl; wz *= iwl;

        float ndotl = fmaxf(wx * Lx + wy * Ly + wz * Lz, 0.0f);
        float ndoth = fmaxf(wx * Hx + wy * Hy + wz * Hz, 0.0f);
        float s2 = ndoth * ndoth, s4 = s2 * s2, s8 = s4 * s4, s16 = s8 * s8;
        float spec = s16 * s16;                   // ndoth^32
        float ndotv = fmaxf(wz, 0.0f);
        float t1 = 1.0f - ndotv;
        float t2 = t1 * t1, t4 = t2 * t2;
        float fres = 0.04f + 0.96f * (t4 * t1);   // Schlick, F0=0.04
        float ka = 0.1f + ndotl;
        float add = spec * fres;

        o[0] = ins ? fminf(fmaxf(__builtin_fmaf(ar, ka, add), 0.0f), 1.0f) : 0.0f;
        o[1] = ins ? fminf(fmaxf(__builtin_fmaf(ag, ka, add), 0.0f), 1.0f) : 0.0f;
        o[2] = ins ? fminf(fmaxf(__builtin_fmaf(ab, ka, add), 0.0f), 1.0f) : 0.0f;
    }
}

extern "C" void kernel_launch(void* const* d_in, const int* in_sizes, int n_in,
                              void* d_out, int out_size, void* d_ws, size_t ws_size,
                              hipStream_t stream) {
    const float* tex  = (const float*)d_in[0];
    const float* nmap = (const float*)d_in[1];
    float* out = (float*)d_out;
    hipLaunchKernelGGL(egg_render, dim3(RESN), dim3(512), 0, stream,
                       tex, nmap, out);
}

// Round 15
// 26.972 us; speedup vs baseline: 1.2828x; 1.0579x over previous
//
#include <hip/hip_runtime.h>
#include <math.h>

#define RESN 2048
#define TEXW 1024

// atan2 for y >= 0, returns [0, pi]. Single-rcp Cephes-style:
// (a-1)/(a+1) == (mn-mx)/(mn+mx), reduction test done pre-division.
// Peak err ~2e-7 rad, ONE v_rcp on the trans pipe (was 2 + Newton).
__device__ __forceinline__ float fatan2_pos(float y, float x) {
    float ax = fabsf(x);
    float mn = fminf(ax, y);
    float mx = fmaxf(ax, y);
    bool red = mn > 0.41421356f * mx;                // a > tan(pi/8)
    float num = red ? (mn - mx) : mn;
    float den = red ? (mn + mx) : mx;
    float w = num * __builtin_amdgcn_rcpf(den);      // |w| <= 0.41421356
    float s = w * w;
    float p = __builtin_fmaf(s, 8.05374449538e-2f, -1.38776856032e-1f);
    p = __builtin_fmaf(s, p, 1.99777106478e-1f);
    p = __builtin_fmaf(s, p, -3.33329491539e-1f);
    float r = __builtin_fmaf(w * s, p, w);           // atan(w)
    r = red ? r + 0.78539816339f : r;                // + pi/4
    r = (y > ax) ? 1.57079632679f - r : r;
    r = (x < 0.0f) ? 3.14159265359f - r : r;
    return r;
}

// 12-byte texel -> global_load_dwordx3
struct __align__(4) F3 { float x, y, z; };

__global__ __launch_bounds__(256) void egg_render(
    const float* __restrict__ tex,
    const float* __restrict__ nmap,
    float* __restrict__ out)
{
    // R10 structure (best measured): 2 px/thread, flat scalars, both addr
    // blocks -> all 16 loads -> shadeA (B's loads in flight) -> shadeB.
    int t = blockIdx.x * 256 + threadIdx.x;          // 2,097,152 threads
    int j = t >> 10;                                  // row
    int tr = t & 1023;
    int iA = ((tr >> 6) << 7) + (tr & 63);            // first half of 128-px segment
    int iB = iA + 64;                                 // second half
    float* oA = out + ((size_t)j * RESN + iA) * 3u;
    float* oB = oA + 192u;

    const float invres = 1.0f / (float)RESN;
    // bit-exact vs numpy on the inside-test path: no fma contraction,
    // true IEEE division by 0.85
    float ny = __fmul_rn(__fsub_rn(0.5f, __fmul_rn((float)j, invres)), 2.0f) / 0.85f;
    float nysq = __fmul_rn(ny, ny);

    if (!(nysq <= 1.0f)) {                            // whole row outside
        oA[0] = 0.f; oA[1] = 0.f; oA[2] = 0.f;
        oB[0] = 0.f; oB[1] = 0.f; oB[2] = 0.f;
        return;
    }

    // ---- row-shared (ny-only) ----
    float egg = 1.0f - 0.25f * ny;                    // in [0.75, 1.25]
    float sphi = sqrtf(fmaxf(__builtin_fmaf(-ny, ny, 1.0f), 0.0f));
    float phi = fatan2_pos(sphi, ny);                 // == acos(ny)
    float v = phi * 0.3183098861837907f;              // /pi, in [0,1]; floor unneeded
    float yy = v * (float)TEXW - 0.5f;
    float yf = floorf(yy);
    float fy = yy - yf;
    float gy = 1.0f - fy;
    int y0 = (int)yf & (TEXW - 1);
    int y1 = (y0 + 1) & (TEXW - 1);
    int rb0 = y0 * TEXW;
    int rb1 = y1 * TEXW;

    // ---- pixel A: address math ----
    float nxA = __fmul_rn(__fsub_rn(__fmul_rn((float)iA, invres), 0.5f), 2.0f) / 0.85f;
    float rsqA = __fadd_rn(__fmul_rn(nxA, nxA), nysq);
    bool inA = (rsqA <= 1.0f);
    float zA = sqrtf(fmaxf(__fsub_rn(1.0f, rsqA), 0.0f));   // 0 for outside lanes
    float thetaA = fatan2_pos(zA, nxA);                      // valid addr for outside lanes too
    float uA = thetaA * 0.15915494309189535f + 0.5f;         // in [0.5,1.0]
    float xxA = uA * (float)TEXW - 0.5f;
    float xfA = floorf(xxA);
    float fxA = xxA - xfA;
    float gxA = 1.0f - fxA;
    int x0A = (int)xfA & (TEXW - 1);
    int x1A = (x0A + 1) & (TEXW - 1);
    float w00A = gxA * gy, w01A = fxA * gy, w10A = gxA * fy, w11A = fxA * fy;
    int o00A = (rb0 + x0A) * 3, o01A = (rb0 + x1A) * 3;
    int o10A = (rb1 + x0A) * 3, o11A = (rb1 + x1A) * 3;

    // ---- pixel B: address math ----
    float nxB = __fmul_rn(__fsub_rn(__fmul_rn((float)iB, invres), 0.5f), 2.0f) / 0.85f;
    float rsqB = __fadd_rn(__fmul_rn(nxB, nxB), nysq);
    bool inB = (rsqB <= 1.0f);
    float zB = sqrtf(fmaxf(__fsub_rn(1.0f, rsqB), 0.0f));
    float thetaB = fatan2_pos(zB, nxB);
    float uB = thetaB * 0.15915494309189535f + 0.5f;
    float xxB = uB * (float)TEXW - 0.5f;
    float xfB = floorf(xxB);
    float fxB = xxB - xfB;
    float gxB = 1.0f - fxB;
    int x0B = (int)xfB & (TEXW - 1);
    int x1B = (x0B + 1) & (TEXW - 1);
    float w00B = gxB * gy, w01B = fxB * gy, w10B = gxB * fy, w11B = fxB * fy;
    int o00B = (rb0 + x0B) * 3, o01B = (rb0 + x1B) * 3;
    int o10B = (rb1 + x0B) * 3, o11B = (rb1 + x1B) * 3;

    // ---- issue all 16 gathers back-to-back ----
    F3 aA00 = *(const F3*)(tex + o00A);
    F3 aA01 = *(const F3*)(tex + o01A);
    F3 aA10 = *(const F3*)(tex + o10A);
    F3 aA11 = *(const F3*)(tex + o11A);
    F3 nA00 = *(const F3*)(nmap + o00A);
    F3 nA01 = *(const F3*)(nmap + o01A);
    F3 nA10 = *(const F3*)(nmap + o10A);
    F3 nA11 = *(const F3*)(nmap + o11A);
    F3 aB00 = *(const F3*)(tex + o00B);
    F3 aB01 = *(const F3*)(tex + o01B);
    F3 aB10 = *(const F3*)(tex + o10B);
    F3 aB11 = *(const F3*)(tex + o11B);
    F3 nB00 = *(const F3*)(nmap + o00B);
    F3 nB01 = *(const F3*)(nmap + o01B);
    F3 nB10 = *(const F3*)(nmap + o10B);
    F3 nB11 = *(const F3*)(nmap + o11B);

    // lighting constants (compile-time folded, f32 semantics)
    float Lx = 0.5f, Ly = 0.7f, Lz = 1.0f;
    float ll = sqrtf(Lx * Lx + Ly * Ly + Lz * Lz);
    Lx /= ll; Ly /= ll; Lz /= ll;
    float Hx = Lx, Hy = Ly, Hz = Lz + 1.0f;
    float hl = sqrtf(Hx * Hx + Hy * Hy + Hz * Hz);
    Hx /= hl; Hy /= hl; Hz /= hl;

    // ---- shade A (B's loads stay in flight) ----
    {
        float ar = aA00.x*w00A + aA01.x*w01A + aA10.x*w10A + aA11.x*w11A;
        float ag = aA00.y*w00A + aA01.y*w01A + aA10.y*w10A + aA11.y*w11A;
        float ab = aA00.z*w00A + aA01.z*w01A + aA10.z*w10A + aA11.z*w11A;
        float tnx = (nA00.x*w00A + nA01.x*w01A + nA10.x*w10A + nA11.x*w11A) * 2.0f - 1.0f;
        float tny = (nA00.y*w00A + nA01.y*w01A + nA10.y*w10A + nA11.y*w11A) * 2.0f - 1.0f;
        float tnz = (nA00.z*w00A + nA01.z*w01A + nA10.z*w10A + nA11.z*w11A) * 2.0f - 1.0f;

        // |w| == |tn| (orthonormal basis): start the rsq early, off the
        // basis-chain critical path.
        float tn2 = tnx*tnx + tny*tny + tnz*tnz;
        float iwl = __builtin_amdgcn_rsqf(fmaxf(tn2, 1e-12f));

        float snx = nxA * egg, sny = ny, snz = zA * egg;
        float sl2 = snx*snx + sny*sny + snz*snz;       // > 0.5 for all lanes
        float isl = __builtin_amdgcn_rsqf(sl2);
        float bnx = snx * isl, bny = sny * isl, bnz = snz * isl;

        bool use_right = fabsf(bny) > 0.99f;
        float d = use_right ? bnx : bny;
        float m = use_right ? bny : bnx;
        float q2 = m * m + bnz * bnz;
        float iq = __builtin_amdgcn_rsqf(q2);
        float q  = q2 * iq;
        float e  = -(d * iq);
        float tzv = bnz * e;
        float tx = use_right ? q : (bnx * e);
        float ty = use_right ? (bny * e) : q;
        float bx = use_right ? 0.0f        : -(bnz * iq);
        float by = use_right ? (bnz * iq)  : 0.0f;
        float bz = use_right ? -(bny * iq) : (bnx * iq);

        float wx = (tnx * tx + tny * bx + tnz * bnx) * iwl;
        float wy = (tnx * ty + tny * by + tnz * bny) * iwl;
        float wz = (tnx * tzv + tny * bz + tnz * bnz) * iwl;

        float ndotl = fmaxf(wx * Lx + wy * Ly + wz * Lz, 0.0f);
        float ndoth = fmaxf(wx * Hx + wy * Hy + wz * Hz, 0.0f);
        float s2 = ndoth * ndoth, s4 = s2 * s2, s8 = s4 * s4, s16 = s8 * s8;
        float spec = s16 * s16;
        float ndotv = fmaxf(wz, 0.0f);
        float t1 = 1.0f - ndotv;
        float t2 = t1 * t1, t4 = t2 * t2;
        float fres = 0.04f + 0.96f * (t4 * t1);
        float ka = 0.1f + ndotl;
        float add = spec * fres;

        oA[0] = inA ? fminf(fmaxf(__builtin_fmaf(ar, ka, add), 0.0f), 1.0f) : 0.0f;
        oA[1] = inA ? fminf(fmaxf(__builtin_fmaf(ag, ka, add), 0.0f), 1.0f) : 0.0f;
        oA[2] = inA ? fminf(fmaxf(__builtin_fmaf(ab, ka, add), 0.0f), 1.0f) : 0.0f;
    }

    // ---- shade B ----
    {
        float ar = aB00.x*w00B + aB01.x*w01B + aB10.x*w10B + aB11.x*w11B;
        float ag = aB00.y*w00B + aB01.y*w01B + aB10.y*w10B + aB11.y*w11B;
        float ab = aB00.z*w00B + aB01.z*w01B + aB10.z*w10B + aB11.z*w11B;
        float tnx = (nB00.x*w00B + nB01.x*w01B + nB10.x*w10B + nB11.x*w11B) * 2.0f - 1.0f;
        float tny = (nB00.y*w00B + nB01.y*w01B + nB10.y*w10B + nB11.y*w11B) * 2.0f - 1.0f;
        float tnz = (nB00.z*w00B + nB01.z*w01B + nB10.z*w10B + nB11.z*w11B) * 2.0f - 1.0f;

        float tn2 = tnx*tnx + tny*tny + tnz*tnz;
        float iwl = __builtin_amdgcn_rsqf(fmaxf(tn2, 1e-12f));

        float snx = nxB * egg, sny = ny, snz = zB * egg;
        float sl2 = snx*snx + sny*sny + snz*snz;
        float isl = __builtin_amdgcn_rsqf(sl2);
        float bnx = snx * isl, bny = sny * isl, bnz = snz * isl;

        bool use_right = fabsf(bny) > 0.99f;
        float d = use_right ? bnx : bny;
        float m = use_right ? bny : bnx;
        float q2 = m * m + bnz * bnz;
        float iq = __builtin_amdgcn_rsqf(q2);
        float q  = q2 * iq;
        float e  = -(d * iq);
        float tzv = bnz * e;
        float tx = use_right ? q : (bnx * e);
        float ty = use_right ? (bny * e) : q;
        float bx = use_right ? 0.0f        : -(bnz * iq);
        float by = use_right ? (bnz * iq)  : 0.0f;
        float bz = use_right ? -(bny * iq) : (bnx * iq);

        float wx = (tnx * tx + tny * bx + tnz * bnx) * iwl;
        float wy = (tnx * ty + tny * by + tnz * bny) * iwl;
        float wz = (tnx * tzv + tny * bz + tnz * bnz) * iwl;

        float ndotl = fmaxf(wx * Lx + wy * Ly + wz * Lz, 0.0f);
        float ndoth = fmaxf(wx * Hx + wy * Hy + wz * Hz, 0.0f);
        float s2 = ndoth * ndoth, s4 = s2 * s2, s8 = s4 * s4, s16 = s8 * s8;
        float spec = s16 * s16;
        float ndotv = fmaxf(wz, 0.0f);
        float t1 = 1.0f - ndotv;
        float t2 = t1 * t1, t4 = t2 * t2;
        float fres = 0.04f + 0.96f * (t4 * t1);
        float ka = 0.1f + ndotl;
        float add = spec * fres;

        oB[0] = inB ? fminf(fmaxf(__builtin_fmaf(ar, ka, add), 0.0f), 1.0f) : 0.0f;
        oB[1] = inB ? fminf(fmaxf(__builtin_fmaf(ag, ka, add), 0.0f), 1.0f) : 0.0f;
        oB[2] = inB ? fminf(fmaxf(__builtin_fmaf(ab, ka, add), 0.0f), 1.0f) : 0.0f;
    }
}

extern "C" void kernel_launch(void* const* d_in, const int* in_sizes, int n_in,
                              void* d_out, int out_size, void* d_ws, size_t ws_size,
                              hipStream_t stream) {
    const float* tex  = (const float*)d_in[0];
    const float* nmap = (const float*)d_in[1];
    float* out = (float*)d_out;
    int total_threads = RESN * RESN / 2;          // 2,097,152
    dim3 grid(total_threads / 256), block(256);   // 8192 blocks
    hipLaunchKernelGGL(egg_render, grid, block, 0, stream, tex, nmap, out);
}